// Round 6
// baseline (2088.396 us; speedup 1.0000x reference)
//
#include <hip/hip_runtime.h>

#define NN   100000
#define EMB  64
#define HID  128
#define OUTD 64
#define NE   1600000
#define NL   200000
#define NBUK 391      // ceil(NN/256) buckets of 256 nodes
#define CAP  5120     // bucket capacity; E[count]=4096, sigma=64 -> 16 sigma margin

// ---------------- bucket edges by dst>>8, pack (dst&255)<<17 | src ----------------
__global__ void bucket_kernel(const int* __restrict__ src, const int* __restrict__ dst,
                              int* __restrict__ bcnt, int* __restrict__ tmp) {
    int i = blockIdx.x * blockDim.x + threadIdx.x;
    if (i >= NE) return;
    int d = dst[i];
    int s = src[i];
    int b = d >> 8;
    int pos = atomicAdd(&bcnt[b], 1);
    if (pos < CAP) tmp[b * CAP + pos] = ((d & 255) << 17) | s;
}

// ---------------- per-bucket LDS aggregation ----------------
// L1=true : out[i] = inv_deg[i] * sum_{j in N(i)} x[j];  also writes inv_deg
// L1=false: out[i] = inv_deg[i] * sum x[j] + hz[i] + b2  (fused z)
template<bool L1>
__global__ void __launch_bounds__(512) agg_kernel(
        const int* __restrict__ bcnt, const int* __restrict__ tmp,
        const float* __restrict__ x, float* __restrict__ invd,
        const float* __restrict__ hz, const float* __restrict__ bias,
        float* __restrict__ outp) {
    __shared__ float sagg[256 * 64];   // 64 KB
    __shared__ int sdeg[256];

    const int b    = blockIdx.x;
    const int tid  = threadIdx.x;
    const int lane = tid & 63;
    const int wv   = tid >> 6;         // 0..7

    for (int i = tid; i < 256 * 64; i += 512) sagg[i] = 0.f;
    if (L1 && tid < 256) sdeg[tid] = 0;
    __syncthreads();

    const int cnt = min(bcnt[b], CAP);
    const int* tb = tmp + b * CAP;

    int e = wv;
    for (; e + 24 < cnt; e += 32) {
        int p0 = tb[e], p1 = tb[e + 8], p2 = tb[e + 16], p3 = tb[e + 24];
        float v0 = x[(size_t)(p0 & 0x1FFFF) * 64 + lane];
        float v1 = x[(size_t)(p1 & 0x1FFFF) * 64 + lane];
        float v2 = x[(size_t)(p2 & 0x1FFFF) * 64 + lane];
        float v3 = x[(size_t)(p3 & 0x1FFFF) * 64 + lane];
        atomicAdd(&sagg[(p0 >> 17) * 64 + lane], v0);
        atomicAdd(&sagg[(p1 >> 17) * 64 + lane], v1);
        atomicAdd(&sagg[(p2 >> 17) * 64 + lane], v2);
        atomicAdd(&sagg[(p3 >> 17) * 64 + lane], v3);
        if (L1 && lane == 0) {
            atomicAdd(&sdeg[p0 >> 17], 1);
            atomicAdd(&sdeg[p1 >> 17], 1);
            atomicAdd(&sdeg[p2 >> 17], 1);
            atomicAdd(&sdeg[p3 >> 17], 1);
        }
    }
    for (; e < cnt; e += 8) {
        int p0 = tb[e];
        float v0 = x[(size_t)(p0 & 0x1FFFF) * 64 + lane];
        atomicAdd(&sagg[(p0 >> 17) * 64 + lane], v0);
        if (L1 && lane == 0) atomicAdd(&sdeg[p0 >> 17], 1);
    }
    __syncthreads();

    const int nbase = b * 256;
    if (L1) {
        for (int r = wv; r < 256; r += 8) {
            int node = nbase + r;
            if (node >= NN) continue;
            float inv = 1.0f / fmaxf((float)sdeg[r], 1.0f);
            if (lane == 0) invd[node] = inv;
            outp[(size_t)node * 64 + lane] = sagg[r * 64 + lane] * inv;
        }
    } else {
        float bb = bias[lane];
        for (int r = wv; r < 256; r += 8) {
            int node = nbase + r;
            if (node >= NN) continue;
            float inv = invd[node];
            outp[(size_t)node * 64 + lane] =
                sagg[r * 64 + lane] * inv + hz[(size_t)node * 64 + lane] + bb;
        }
    }
}

// ---------------- tiled GEMM: 128 nodes x 128 outs per block, K=128 blocked by 64 ----
// MODE 1 (layer 1): X = cat(agg, emb), W = cat_c(w1l, w1r), out = relu(XW^T + b1)
// MODE 2 (layer 2): X = h, W rows: o<64 w2l[o], o>=64 w2r[o-64]; outs->outA(p2)/outB(hz)
template<int MODE>
__global__ void __launch_bounds__(512, 1) gemm_kernel(
        const float* __restrict__ Xa, const float* __restrict__ Xb,
        const float* __restrict__ Wa, const float* __restrict__ Wb,
        const float* __restrict__ bias,
        float* __restrict__ outA, float* __restrict__ outB) {
    __shared__ float lds_x[64 * 128];  // [c_local][node_local]
    __shared__ float lds_w[64 * 128];  // [c_local][o]

    const int tid = threadIdx.x;
    const int n_base = blockIdx.x * 128;

    const int ng = tid & 31;   // nodes 4*ng .. 4*ng+3
    const int og = tid >> 5;   // outs  8*og .. 8*og+7
    const int o0 = og * 8;

    float acc[4][8];
#pragma unroll
    for (int i = 0; i < 4; ++i)
#pragma unroll
        for (int j = 0; j < 8; ++j) acc[i][j] = 0.f;

#pragma unroll
    for (int half = 0; half < 2; ++half) {
        // ---- stage W half (transposed): lds_w[c][o] ----
        {
            int o = tid >> 2;
            int wslot = tid & 3;
#pragma unroll
            for (int k = 0; k < 4; ++k) {
                int s = wslot + 4 * k;   // float4 slot 0..15 within 64 c's
                int c4 = s * 4;          // local c
                float4 v;
                if (MODE == 1) {
                    v = (half == 0) ? ((const float4*)Wa)[o * 16 + s]
                                    : ((const float4*)Wb)[o * 16 + s];
                } else {
                    int cg4 = half * 16 + s;
                    v = (o < 64) ? ((const float4*)Wa)[o * 32 + cg4]
                                 : ((const float4*)Wb)[(o - 64) * 32 + cg4];
                }
                lds_w[(c4 + 0) * 128 + o] = v.x;
                lds_w[(c4 + 1) * 128 + o] = v.y;
                lds_w[(c4 + 2) * 128 + o] = v.z;
                lds_w[(c4 + 3) * 128 + o] = v.w;
            }
        }
        // ---- stage X half (transposed): lds_x[c][n_local] ----
        {
            int nl = tid >> 2;
            int cslot = tid & 3;
            int n = n_base + nl;
            bool ok = n < NN;
#pragma unroll
            for (int k = 0; k < 4; ++k) {
                int s = cslot + 4 * k;   // 0..15
                int c4 = s * 4;
                float4 v = make_float4(0.f, 0.f, 0.f, 0.f);
                if (ok) {
                    if (MODE == 1) {
                        v = (half == 0) ? ((const float4*)Xa)[(size_t)n * 16 + s]
                                        : ((const float4*)Xb)[(size_t)n * 16 + s];
                    } else {
                        v = ((const float4*)Xa)[(size_t)n * 32 + half * 16 + s];
                    }
                }
                lds_x[(c4 + 0) * 128 + nl] = v.x;
                lds_x[(c4 + 1) * 128 + nl] = v.y;
                lds_x[(c4 + 2) * 128 + nl] = v.z;
                lds_x[(c4 + 3) * 128 + nl] = v.w;
            }
        }
        __syncthreads();

        // ---- compute half ----
#pragma unroll 2
        for (int c = 0; c < 64; ++c) {
            float4 xv = *(const float4*)&lds_x[c * 128 + ng * 4];
            float4 w0 = *(const float4*)&lds_w[c * 128 + o0];
            float4 w1 = *(const float4*)&lds_w[c * 128 + o0 + 4];
            float xr[4] = {xv.x, xv.y, xv.z, xv.w};
            float wr[8] = {w0.x, w0.y, w0.z, w0.w, w1.x, w1.y, w1.z, w1.w};
#pragma unroll
            for (int i = 0; i < 4; ++i)
#pragma unroll
                for (int j = 0; j < 8; ++j) acc[i][j] += xr[i] * wr[j];
        }
        __syncthreads();
    }

    // ---- epilogue ----
    if (MODE == 1) {
        float bj[8];
#pragma unroll
        for (int j = 0; j < 8; ++j) bj[j] = bias[o0 + j];
#pragma unroll
        for (int i = 0; i < 4; ++i) {
            int n = n_base + ng * 4 + i;
            if (n >= NN) continue;
            float4 lo = make_float4(fmaxf(acc[i][0] + bj[0], 0.f), fmaxf(acc[i][1] + bj[1], 0.f),
                                    fmaxf(acc[i][2] + bj[2], 0.f), fmaxf(acc[i][3] + bj[3], 0.f));
            float4 hi = make_float4(fmaxf(acc[i][4] + bj[4], 0.f), fmaxf(acc[i][5] + bj[5], 0.f),
                                    fmaxf(acc[i][6] + bj[6], 0.f), fmaxf(acc[i][7] + bj[7], 0.f));
            ((float4*)outA)[(size_t)n * 32 + (o0 >> 2)] = lo;
            ((float4*)outA)[(size_t)n * 32 + (o0 >> 2) + 1] = hi;
        }
    } else {
        float* dstp = (og < 8) ? outA : outB;
        int ob = (og < 8) ? o0 : (o0 - 64);
#pragma unroll
        for (int i = 0; i < 4; ++i) {
            int n = n_base + ng * 4 + i;
            if (n >= NN) continue;
            float4 lo = make_float4(acc[i][0], acc[i][1], acc[i][2], acc[i][3]);
            float4 hi = make_float4(acc[i][4], acc[i][5], acc[i][6], acc[i][7]);
            ((float4*)dstp)[(size_t)n * 16 + (ob >> 2)] = lo;
            ((float4*)dstp)[(size_t)n * 16 + (ob >> 2) + 1] = hi;
        }
    }
}

// ---------------- decode: out[k] = dot(z[a[k]], z[b[k]]) ----------------
__global__ void decode_kernel(const int* __restrict__ a, const int* __restrict__ b,
                              const float* __restrict__ z, float* __restrict__ out) {
    int t = blockIdx.x * blockDim.x + threadIdx.x;
    int k = t >> 4;
    int q = t & 15;
    if (k >= NL) return;
    int ia = a[k], ib = b[k];
    float4 va = ((const float4*)z)[ia * 16 + q];
    float4 vb = ((const float4*)z)[ib * 16 + q];
    float s = va.x * vb.x + va.y * vb.y + va.z * vb.z + va.w * vb.w;
    s += __shfl_xor(s, 1, 64);
    s += __shfl_xor(s, 2, 64);
    s += __shfl_xor(s, 4, 64);
    s += __shfl_xor(s, 8, 64);
    if (q == 0) out[k] = s;
}

extern "C" void kernel_launch(void* const* d_in, const int* in_sizes, int n_in,
                              void* d_out, int out_size, void* d_ws, size_t ws_size,
                              hipStream_t stream) {
    const float* emb = (const float*)d_in[0];
    const float* w1l = (const float*)d_in[1];
    const float* w1r = (const float*)d_in[2];
    const float* b1  = (const float*)d_in[3];
    const float* w2l = (const float*)d_in[4];
    const float* w2r = (const float*)d_in[5];
    const float* b2  = (const float*)d_in[6];
    const int*   ei  = (const int*)d_in[7];
    const int*   eli = (const int*)d_in[8];
    float* out = (float*)d_out;

    // workspace layout (~110.8 MB)
    int* bcnt    = (int*)d_ws;                        // 512 (391 used)
    int* tmp     = bcnt + 512;                        // NBUK*CAP = 2,002,720
    float* invd  = (float*)(tmp + NBUK * CAP);        // NN
    float* agg   = invd + NN;                         // NN*64 (reused as hz)
    float* h     = agg + (size_t)NN * 64;             // NN*128 (reused as z)
    float* p2    = h + (size_t)NN * 128;              // NN*64
    float* hz    = agg;
    float* z     = h;

    const int* src = ei;
    const int* dst = ei + NE;

    hipMemsetAsync(bcnt, 0, 512 * sizeof(int), stream);

    // bucket edges by dst>>8
    bucket_kernel<<<(NE + 255) / 256, 256, 0, stream>>>(src, dst, bcnt, tmp);

    const int NT = (NN + 127) / 128;  // 782 tiles

    // layer 1: agg = mean-gather(emb) via LDS; h = relu(cat(agg,emb) @ cat(w1l,w1r)^T + b1)
    agg_kernel<true><<<NBUK, 512, 0, stream>>>(bcnt, tmp, emb, invd, nullptr, nullptr, agg);
    gemm_kernel<1><<<NT, 512, 0, stream>>>(agg, emb, w1l, w1r, b1, h, nullptr);

    // layer 2: {p2, hz} = h @ {w2l, w2r}^T ; z = mean-gather(p2) + hz + b2
    gemm_kernel<2><<<NT, 512, 0, stream>>>(h, nullptr, w2l, w2r, nullptr, p2, hz);
    agg_kernel<false><<<NBUK, 512, 0, stream>>>(bcnt, tmp, p2, invd, hz, b2, z);

    // decode
    decode_kernel<<<(NL * 16 + 255) / 256, 256, 0, stream>>>(eli, eli + NL, z, out);
}

// Round 7
// 1270.348 us; speedup vs baseline: 1.6440x; 1.6440x over previous
//
#include <hip/hip_runtime.h>

#define NN   100000
#define EMB  64
#define HID  128
#define OUTD 64
#define NE   1600000
#define NL   200000
#define NBUK 6250     // NN/16 buckets of exactly 16 nodes
#define CAP  384      // bucket capacity; E[count]=256, Poisson sigma=16 -> 8 sigma margin

// ---------------- bucket edges by dst>>4, pack (dst&15)<<17 | src ----------------
__global__ void bucket16_kernel(const int* __restrict__ src, const int* __restrict__ dst,
                                int* __restrict__ bcnt, int* __restrict__ tmp) {
    int i = blockIdx.x * blockDim.x + threadIdx.x;
    if (i >= NE) return;
    int d = dst[i];
    int s = src[i];
    int b = d >> 4;
    int pos = atomicAdd(&bcnt[b], 1);
    if (pos < CAP) tmp[b * CAP + pos] = ((d & 15) << 17) | s;
}

// ---------------- per-bucket (16 nodes) LDS aggregation ----------------
// L1=true : out[i] = inv_deg[i] * sum_{j in N(i)} x[j]; also writes inv_deg (deg counted here)
// L1=false: out[i] = inv_deg[i] * sum x[j] + hz[i] + bias  (fused z)
template<bool L1>
__global__ void __launch_bounds__(256) agg16_kernel(
        const int* __restrict__ bcnt, const int* __restrict__ tmp,
        const float* __restrict__ x, float* __restrict__ invd,
        const float* __restrict__ hz, const float* __restrict__ bias,
        float* __restrict__ outp) {
    __shared__ float sagg[16 * 64];   // 4 KB
    __shared__ int sdeg[16];

    const int b    = blockIdx.x;
    const int tid  = threadIdx.x;
    const int lane = tid & 63;
    const int wv   = tid >> 6;         // 0..3

    for (int i = tid; i < 16 * 64; i += 256) sagg[i] = 0.f;
    if (L1 && tid < 16) sdeg[tid] = 0;
    __syncthreads();

    const int cnt = min(bcnt[b], CAP);
    const int* tb = tmp + b * CAP;

    int e = wv;
    // 8-deep unroll, per-wave stride 4, step 32: 8 independent row loads in flight
    for (; e + 28 < cnt; e += 32) {
        int p[8];
        float v[8];
#pragma unroll
        for (int k = 0; k < 8; ++k) p[k] = tb[e + 4 * k];
#pragma unroll
        for (int k = 0; k < 8; ++k) v[k] = x[(size_t)(p[k] & 0x1FFFF) * 64 + lane];
#pragma unroll
        for (int k = 0; k < 8; ++k) atomicAdd(&sagg[(p[k] >> 17) * 64 + lane], v[k]);
        if (L1 && lane == 0) {
#pragma unroll
            for (int k = 0; k < 8; ++k) atomicAdd(&sdeg[p[k] >> 17], 1);
        }
    }
    for (; e < cnt; e += 4) {
        int p0 = tb[e];
        float v0 = x[(size_t)(p0 & 0x1FFFF) * 64 + lane];
        atomicAdd(&sagg[(p0 >> 17) * 64 + lane], v0);
        if (L1 && lane == 0) atomicAdd(&sdeg[p0 >> 17], 1);
    }
    __syncthreads();

    for (int r = wv; r < 16; r += 4) {
        int node = b * 16 + r;
        if (L1) {
            float inv = 1.0f / fmaxf((float)sdeg[r], 1.0f);
            if (lane == 0) invd[node] = inv;
            outp[(size_t)node * 64 + lane] = sagg[r * 64 + lane] * inv;
        } else {
            outp[(size_t)node * 64 + lane] =
                sagg[r * 64 + lane] * invd[node] + hz[(size_t)node * 64 + lane] + bias[lane];
        }
    }
}

// ---------------- tiled GEMM: 128 nodes x 128 outs per block, K=128 blocked by 64 ----
// MODE 1 (layer 1): X = cat(agg, emb), W = cat_c(w1l, w1r), out = relu(XW^T + b1)
// MODE 2 (layer 2): X = h, W rows: o<64 w2l[o], o>=64 w2r[o-64]; outs->outA(p2)/outB(hz)
template<int MODE>
__global__ void __launch_bounds__(512, 1) gemm_kernel(
        const float* __restrict__ Xa, const float* __restrict__ Xb,
        const float* __restrict__ Wa, const float* __restrict__ Wb,
        const float* __restrict__ bias,
        float* __restrict__ outA, float* __restrict__ outB) {
    __shared__ float lds_x[64 * 128];  // [c_local][node_local]
    __shared__ float lds_w[64 * 128];  // [c_local][o]

    const int tid = threadIdx.x;
    const int n_base = blockIdx.x * 128;

    const int ng = tid & 31;   // nodes 4*ng .. 4*ng+3
    const int og = tid >> 5;   // outs  8*og .. 8*og+7
    const int o0 = og * 8;

    float acc[4][8];
#pragma unroll
    for (int i = 0; i < 4; ++i)
#pragma unroll
        for (int j = 0; j < 8; ++j) acc[i][j] = 0.f;

#pragma unroll
    for (int half = 0; half < 2; ++half) {
        // ---- stage W half (transposed): lds_w[c][o] ----
        {
            int o = tid >> 2;
            int wslot = tid & 3;
#pragma unroll
            for (int k = 0; k < 4; ++k) {
                int s = wslot + 4 * k;   // float4 slot 0..15 within 64 c's
                int c4 = s * 4;          // local c
                float4 v;
                if (MODE == 1) {
                    v = (half == 0) ? ((const float4*)Wa)[o * 16 + s]
                                    : ((const float4*)Wb)[o * 16 + s];
                } else {
                    int cg4 = half * 16 + s;
                    v = (o < 64) ? ((const float4*)Wa)[o * 32 + cg4]
                                 : ((const float4*)Wb)[(o - 64) * 32 + cg4];
                }
                lds_w[(c4 + 0) * 128 + o] = v.x;
                lds_w[(c4 + 1) * 128 + o] = v.y;
                lds_w[(c4 + 2) * 128 + o] = v.z;
                lds_w[(c4 + 3) * 128 + o] = v.w;
            }
        }
        // ---- stage X half (transposed): lds_x[c][n_local] ----
        {
            int nl = tid >> 2;
            int cslot = tid & 3;
            int n = n_base + nl;
            bool ok = n < NN;
#pragma unroll
            for (int k = 0; k < 4; ++k) {
                int s = cslot + 4 * k;   // 0..15
                int c4 = s * 4;
                float4 v = make_float4(0.f, 0.f, 0.f, 0.f);
                if (ok) {
                    if (MODE == 1) {
                        v = (half == 0) ? ((const float4*)Xa)[(size_t)n * 16 + s]
                                        : ((const float4*)Xb)[(size_t)n * 16 + s];
                    } else {
                        v = ((const float4*)Xa)[(size_t)n * 32 + half * 16 + s];
                    }
                }
                lds_x[(c4 + 0) * 128 + nl] = v.x;
                lds_x[(c4 + 1) * 128 + nl] = v.y;
                lds_x[(c4 + 2) * 128 + nl] = v.z;
                lds_x[(c4 + 3) * 128 + nl] = v.w;
            }
        }
        __syncthreads();

        // ---- compute half ----
#pragma unroll 2
        for (int c = 0; c < 64; ++c) {
            float4 xv = *(const float4*)&lds_x[c * 128 + ng * 4];
            float4 w0 = *(const float4*)&lds_w[c * 128 + o0];
            float4 w1 = *(const float4*)&lds_w[c * 128 + o0 + 4];
            float xr[4] = {xv.x, xv.y, xv.z, xv.w};
            float wr[8] = {w0.x, w0.y, w0.z, w0.w, w1.x, w1.y, w1.z, w1.w};
#pragma unroll
            for (int i = 0; i < 4; ++i)
#pragma unroll
                for (int j = 0; j < 8; ++j) acc[i][j] += xr[i] * wr[j];
        }
        __syncthreads();
    }

    // ---- epilogue ----
    if (MODE == 1) {
        float bj[8];
#pragma unroll
        for (int j = 0; j < 8; ++j) bj[j] = bias[o0 + j];
#pragma unroll
        for (int i = 0; i < 4; ++i) {
            int n = n_base + ng * 4 + i;
            if (n >= NN) continue;
            float4 lo = make_float4(fmaxf(acc[i][0] + bj[0], 0.f), fmaxf(acc[i][1] + bj[1], 0.f),
                                    fmaxf(acc[i][2] + bj[2], 0.f), fmaxf(acc[i][3] + bj[3], 0.f));
            float4 hi = make_float4(fmaxf(acc[i][4] + bj[4], 0.f), fmaxf(acc[i][5] + bj[5], 0.f),
                                    fmaxf(acc[i][6] + bj[6], 0.f), fmaxf(acc[i][7] + bj[7], 0.f));
            ((float4*)outA)[(size_t)n * 32 + (o0 >> 2)] = lo;
            ((float4*)outA)[(size_t)n * 32 + (o0 >> 2) + 1] = hi;
        }
    } else {
        float* dstp = (og < 8) ? outA : outB;
        int ob = (og < 8) ? o0 : (o0 - 64);
#pragma unroll
        for (int i = 0; i < 4; ++i) {
            int n = n_base + ng * 4 + i;
            if (n >= NN) continue;
            float4 lo = make_float4(acc[i][0], acc[i][1], acc[i][2], acc[i][3]);
            float4 hi = make_float4(acc[i][4], acc[i][5], acc[i][6], acc[i][7]);
            ((float4*)dstp)[(size_t)n * 16 + (ob >> 2)] = lo;
            ((float4*)dstp)[(size_t)n * 16 + (ob >> 2) + 1] = hi;
        }
    }
}

// ---------------- decode: out[k] = dot(z[a[k]], z[b[k]]) ----------------
__global__ void decode_kernel(const int* __restrict__ a, const int* __restrict__ b,
                              const float* __restrict__ z, float* __restrict__ out) {
    int t = blockIdx.x * blockDim.x + threadIdx.x;
    int k = t >> 4;
    int q = t & 15;
    if (k >= NL) return;
    int ia = a[k], ib = b[k];
    float4 va = ((const float4*)z)[ia * 16 + q];
    float4 vb = ((const float4*)z)[ib * 16 + q];
    float s = va.x * vb.x + va.y * vb.y + va.z * vb.z + va.w * vb.w;
    s += __shfl_xor(s, 1, 64);
    s += __shfl_xor(s, 2, 64);
    s += __shfl_xor(s, 4, 64);
    s += __shfl_xor(s, 8, 64);
    if (q == 0) out[k] = s;
}

extern "C" void kernel_launch(void* const* d_in, const int* in_sizes, int n_in,
                              void* d_out, int out_size, void* d_ws, size_t ws_size,
                              hipStream_t stream) {
    const float* emb = (const float*)d_in[0];
    const float* w1l = (const float*)d_in[1];
    const float* w1r = (const float*)d_in[2];
    const float* b1  = (const float*)d_in[3];
    const float* w2l = (const float*)d_in[4];
    const float* w2r = (const float*)d_in[5];
    const float* b2  = (const float*)d_in[6];
    const int*   ei  = (const int*)d_in[7];
    const int*   eli = (const int*)d_in[8];
    float* out = (float*)d_out;

    // workspace layout (~112 MB)
    int* bcnt    = (int*)d_ws;                        // 6272 (6250 used, padded)
    int* tmp     = bcnt + 6272;                       // NBUK*CAP = 2,400,000
    float* invd  = (float*)(tmp + NBUK * CAP);        // NN
    float* agg   = invd + NN;                         // NN*64 (reused as hz)
    float* h     = agg + (size_t)NN * 64;             // NN*128 (reused as z)
    float* p2    = h + (size_t)NN * 128;              // NN*64
    float* hz    = agg;
    float* z     = h;

    const int* src = ei;
    const int* dst = ei + NE;

    hipMemsetAsync(bcnt, 0, 6272 * sizeof(int), stream);

    // bucket edges by dst>>4 (write-combined, low cursor contention)
    bucket16_kernel<<<(NE + 255) / 256, 256, 0, stream>>>(src, dst, bcnt, tmp);

    const int NT = (NN + 127) / 128;  // 782 tiles

    // layer 1: agg = mean-gather(emb) via LDS (+deg); h = relu(cat(agg,emb) @ cat(w1l,w1r)^T + b1)
    agg16_kernel<true><<<NBUK, 256, 0, stream>>>(bcnt, tmp, emb, invd, nullptr, nullptr, agg);
    gemm_kernel<1><<<NT, 512, 0, stream>>>(agg, emb, w1l, w1r, b1, h, nullptr);

    // layer 2: {p2, hz} = h @ {w2l, w2r}^T ; z = mean-gather(p2) + hz + b2
    gemm_kernel<2><<<NT, 512, 0, stream>>>(h, nullptr, w2l, w2r, nullptr, p2, hz);
    agg16_kernel<false><<<NBUK, 256, 0, stream>>>(bcnt, tmp, p2, invd, hz, b2, z);

    // decode
    decode_kernel<<<(NL * 16 + 255) / 256, 256, 0, stream>>>(eli, eli + NL, z, out);
}

// Round 8
// 335.488 us; speedup vs baseline: 6.2249x; 3.7866x over previous
//
#include <hip/hip_runtime.h>

#define NN   100000
#define EMB  64
#define HID  128
#define OUTD 64
#define NE   1600000
#define NL   200000
#define NBUK 6250     // NN/16 buckets of exactly 16 nodes
#define CAP  384      // bucket capacity; E[count]=256, sigma=16 -> 8 sigma margin

// ---------------- bucket edges by dst>>4, pack (dst&15)<<17 | src ----------------
__global__ void bucket16_kernel(const int* __restrict__ src, const int* __restrict__ dst,
                                int* __restrict__ bcnt, int* __restrict__ tmp) {
    int i = blockIdx.x * blockDim.x + threadIdx.x;
    if (i >= NE) return;
    int d = dst[i];
    int s = src[i];
    int b = d >> 4;
    int pos = atomicAdd(&bcnt[b], 1);
    if (pos < CAP) tmp[b * CAP + pos] = ((d & 15) << 17) | s;
}

// ---------------- per-bucket aggregation via LDS micro-CSR + register gather -------
// L1=true : out[i] = (1/max(deg,1)) * sum_{j in N(i)} x[j]
// L1=false: out[i] = (1/max(deg,1)) * sum x[j] + hz[i] + bias   (fused z)
template<bool L1>
__global__ void __launch_bounds__(256) agg16_kernel(
        const int* __restrict__ bcnt, const int* __restrict__ tmp,
        const float* __restrict__ x,
        const float* __restrict__ hz, const float* __restrict__ bias,
        float* __restrict__ outp) {
    __shared__ int scnt[16];
    __shared__ int soff[16];
    __shared__ int scur[16];
    __shared__ int slist[CAP];

    const int b    = blockIdx.x;
    const int tid  = threadIdx.x;
    const int lane = tid & 63;
    const int wv   = tid >> 6;         // 0..3

    if (tid < 16) scnt[tid] = 0;
    __syncthreads();

    const int cnt = min(bcnt[b], CAP);
    const int* tb = tmp + b * CAP;

    // phase 1: per-node counts (also = degree)
    for (int i = tid; i < cnt; i += 256)
        atomicAdd(&scnt[tb[i] >> 17], 1);
    __syncthreads();

    // phase 2: exclusive scan of 16
    if (tid == 0) {
        int acc = 0;
        for (int r = 0; r < 16; ++r) {
            soff[r] = acc;
            scur[r] = acc;
            acc += scnt[r];
        }
    }
    __syncthreads();

    // phase 3: scatter src ids into per-node lists
    for (int i = tid; i < cnt; i += 256) {
        int p = tb[i];
        int pos = atomicAdd(&scur[p >> 17], 1);
        slist[pos] = p & 0x1FFFF;
    }
    __syncthreads();

    // phase 4: per-node register gather; wave wv owns nodes wv, wv+4, wv+8, wv+12
    for (int r = wv; r < 16; r += 4) {
        const int node = b * 16 + r;
        const int s = soff[r];
        const int d = scnt[r];
        float acc = 0.f;
        int j = 0;
        for (; j + 8 <= d; j += 8) {
            int c0 = slist[s + j + 0], c1 = slist[s + j + 1];
            int c2 = slist[s + j + 2], c3 = slist[s + j + 3];
            int c4 = slist[s + j + 4], c5 = slist[s + j + 5];
            int c6 = slist[s + j + 6], c7 = slist[s + j + 7];
            float v0 = x[(size_t)c0 * 64 + lane];
            float v1 = x[(size_t)c1 * 64 + lane];
            float v2 = x[(size_t)c2 * 64 + lane];
            float v3 = x[(size_t)c3 * 64 + lane];
            float v4 = x[(size_t)c4 * 64 + lane];
            float v5 = x[(size_t)c5 * 64 + lane];
            float v6 = x[(size_t)c6 * 64 + lane];
            float v7 = x[(size_t)c7 * 64 + lane];
            acc += ((v0 + v1) + (v2 + v3)) + ((v4 + v5) + (v6 + v7));
        }
        if (j + 4 <= d) {
            int c0 = slist[s + j + 0], c1 = slist[s + j + 1];
            int c2 = slist[s + j + 2], c3 = slist[s + j + 3];
            float v0 = x[(size_t)c0 * 64 + lane];
            float v1 = x[(size_t)c1 * 64 + lane];
            float v2 = x[(size_t)c2 * 64 + lane];
            float v3 = x[(size_t)c3 * 64 + lane];
            acc += (v0 + v1) + (v2 + v3);
            j += 4;
        }
        for (; j < d; ++j) acc += x[(size_t)slist[s + j] * 64 + lane];

        const float inv = 1.0f / fmaxf((float)d, 1.0f);
        if (L1) {
            outp[(size_t)node * 64 + lane] = acc * inv;
        } else {
            outp[(size_t)node * 64 + lane] =
                acc * inv + hz[(size_t)node * 64 + lane] + bias[lane];
        }
    }
}

// ---------------- tiled GEMM: 128 nodes x 128 outs per block, K=128 blocked by 64 ----
// MODE 1 (layer 1): X = cat(agg, emb), W = cat_c(w1l, w1r), out = relu(XW^T + b1)
// MODE 2 (layer 2): X = h, W rows: o<64 w2l[o], o>=64 w2r[o-64]; outs->outA(p2)/outB(hz)
template<int MODE>
__global__ void __launch_bounds__(512, 1) gemm_kernel(
        const float* __restrict__ Xa, const float* __restrict__ Xb,
        const float* __restrict__ Wa, const float* __restrict__ Wb,
        const float* __restrict__ bias,
        float* __restrict__ outA, float* __restrict__ outB) {
    __shared__ float lds_x[64 * 128];  // [c_local][node_local]
    __shared__ float lds_w[64 * 128];  // [c_local][o]

    const int tid = threadIdx.x;
    const int n_base = blockIdx.x * 128;

    const int ng = tid & 31;   // nodes 4*ng .. 4*ng+3
    const int og = tid >> 5;   // outs  8*og .. 8*og+7
    const int o0 = og * 8;

    float acc[4][8];
#pragma unroll
    for (int i = 0; i < 4; ++i)
#pragma unroll
        for (int j = 0; j < 8; ++j) acc[i][j] = 0.f;

#pragma unroll
    for (int half = 0; half < 2; ++half) {
        // ---- stage W half (transposed): lds_w[c][o] ----
        {
            int o = tid >> 2;
            int wslot = tid & 3;
#pragma unroll
            for (int k = 0; k < 4; ++k) {
                int s = wslot + 4 * k;   // float4 slot 0..15 within 64 c's
                int c4 = s * 4;          // local c
                float4 v;
                if (MODE == 1) {
                    v = (half == 0) ? ((const float4*)Wa)[o * 16 + s]
                                    : ((const float4*)Wb)[o * 16 + s];
                } else {
                    int cg4 = half * 16 + s;
                    v = (o < 64) ? ((const float4*)Wa)[o * 32 + cg4]
                                 : ((const float4*)Wb)[(o - 64) * 32 + cg4];
                }
                lds_w[(c4 + 0) * 128 + o] = v.x;
                lds_w[(c4 + 1) * 128 + o] = v.y;
                lds_w[(c4 + 2) * 128 + o] = v.z;
                lds_w[(c4 + 3) * 128 + o] = v.w;
            }
        }
        // ---- stage X half (transposed): lds_x[c][n_local] ----
        {
            int nl = tid >> 2;
            int cslot = tid & 3;
            int n = n_base + nl;
            bool ok = n < NN;
#pragma unroll
            for (int k = 0; k < 4; ++k) {
                int s = cslot + 4 * k;   // 0..15
                int c4 = s * 4;
                float4 v = make_float4(0.f, 0.f, 0.f, 0.f);
                if (ok) {
                    if (MODE == 1) {
                        v = (half == 0) ? ((const float4*)Xa)[(size_t)n * 16 + s]
                                        : ((const float4*)Xb)[(size_t)n * 16 + s];
                    } else {
                        v = ((const float4*)Xa)[(size_t)n * 32 + half * 16 + s];
                    }
                }
                lds_x[(c4 + 0) * 128 + nl] = v.x;
                lds_x[(c4 + 1) * 128 + nl] = v.y;
                lds_x[(c4 + 2) * 128 + nl] = v.z;
                lds_x[(c4 + 3) * 128 + nl] = v.w;
            }
        }
        __syncthreads();

        // ---- compute half ----
#pragma unroll 2
        for (int c = 0; c < 64; ++c) {
            float4 xv = *(const float4*)&lds_x[c * 128 + ng * 4];
            float4 w0 = *(const float4*)&lds_w[c * 128 + o0];
            float4 w1 = *(const float4*)&lds_w[c * 128 + o0 + 4];
            float xr[4] = {xv.x, xv.y, xv.z, xv.w};
            float wr[8] = {w0.x, w0.y, w0.z, w0.w, w1.x, w1.y, w1.z, w1.w};
#pragma unroll
            for (int i = 0; i < 4; ++i)
#pragma unroll
                for (int j = 0; j < 8; ++j) acc[i][j] += xr[i] * wr[j];
        }
        __syncthreads();
    }

    // ---- epilogue ----
    if (MODE == 1) {
        float bj[8];
#pragma unroll
        for (int j = 0; j < 8; ++j) bj[j] = bias[o0 + j];
#pragma unroll
        for (int i = 0; i < 4; ++i) {
            int n = n_base + ng * 4 + i;
            if (n >= NN) continue;
            float4 lo = make_float4(fmaxf(acc[i][0] + bj[0], 0.f), fmaxf(acc[i][1] + bj[1], 0.f),
                                    fmaxf(acc[i][2] + bj[2], 0.f), fmaxf(acc[i][3] + bj[3], 0.f));
            float4 hi = make_float4(fmaxf(acc[i][4] + bj[4], 0.f), fmaxf(acc[i][5] + bj[5], 0.f),
                                    fmaxf(acc[i][6] + bj[6], 0.f), fmaxf(acc[i][7] + bj[7], 0.f));
            ((float4*)outA)[(size_t)n * 32 + (o0 >> 2)] = lo;
            ((float4*)outA)[(size_t)n * 32 + (o0 >> 2) + 1] = hi;
        }
    } else {
        float* dstp = (og < 8) ? outA : outB;
        int ob = (og < 8) ? o0 : (o0 - 64);
#pragma unroll
        for (int i = 0; i < 4; ++i) {
            int n = n_base + ng * 4 + i;
            if (n >= NN) continue;
            float4 lo = make_float4(acc[i][0], acc[i][1], acc[i][2], acc[i][3]);
            float4 hi = make_float4(acc[i][4], acc[i][5], acc[i][6], acc[i][7]);
            ((float4*)dstp)[(size_t)n * 16 + (ob >> 2)] = lo;
            ((float4*)dstp)[(size_t)n * 16 + (ob >> 2) + 1] = hi;
        }
    }
}

// ---------------- decode: out[k] = dot(z[a[k]], z[b[k]]) ----------------
__global__ void decode_kernel(const int* __restrict__ a, const int* __restrict__ b,
                              const float* __restrict__ z, float* __restrict__ out) {
    int t = blockIdx.x * blockDim.x + threadIdx.x;
    int k = t >> 4;
    int q = t & 15;
    if (k >= NL) return;
    int ia = a[k], ib = b[k];
    float4 va = ((const float4*)z)[ia * 16 + q];
    float4 vb = ((const float4*)z)[ib * 16 + q];
    float s = va.x * vb.x + va.y * vb.y + va.z * vb.z + va.w * vb.w;
    s += __shfl_xor(s, 1, 64);
    s += __shfl_xor(s, 2, 64);
    s += __shfl_xor(s, 4, 64);
    s += __shfl_xor(s, 8, 64);
    if (q == 0) out[k] = s;
}

extern "C" void kernel_launch(void* const* d_in, const int* in_sizes, int n_in,
                              void* d_out, int out_size, void* d_ws, size_t ws_size,
                              hipStream_t stream) {
    const float* emb = (const float*)d_in[0];
    const float* w1l = (const float*)d_in[1];
    const float* w1r = (const float*)d_in[2];
    const float* b1  = (const float*)d_in[3];
    const float* w2l = (const float*)d_in[4];
    const float* w2r = (const float*)d_in[5];
    const float* b2  = (const float*)d_in[6];
    const int*   ei  = (const int*)d_in[7];
    const int*   eli = (const int*)d_in[8];
    float* out = (float*)d_out;

    // workspace layout (~112 MB)
    int* bcnt    = (int*)d_ws;                        // 6272 (6250 used, padded)
    int* tmp     = bcnt + 6272;                       // NBUK*CAP = 2,400,000
    float* agg   = (float*)(tmp + NBUK * CAP);        // NN*64 (reused as hz)
    float* h     = agg + (size_t)NN * 64;             // NN*128 (reused as z)
    float* p2    = h + (size_t)NN * 128;              // NN*64
    float* hz    = agg;
    float* z     = h;

    const int* src = ei;
    const int* dst = ei + NE;

    hipMemsetAsync(bcnt, 0, 6272 * sizeof(int), stream);

    // bucket edges by dst>>4 (write-combined, low cursor contention)
    bucket16_kernel<<<(NE + 255) / 256, 256, 0, stream>>>(src, dst, bcnt, tmp);

    const int NT = (NN + 127) / 128;  // 782 tiles

    // layer 1: agg = mean-gather(emb); h = relu(cat(agg,emb) @ cat(w1l,w1r)^T + b1)
    agg16_kernel<true><<<NBUK, 256, 0, stream>>>(bcnt, tmp, emb, nullptr, nullptr, agg);
    gemm_kernel<1><<<NT, 512, 0, stream>>>(agg, emb, w1l, w1r, b1, h, nullptr);

    // layer 2: {p2, hz} = h @ {w2l, w2r}^T ; z = mean-gather(p2) + hz + b2
    gemm_kernel<2><<<NT, 512, 0, stream>>>(h, nullptr, w2l, w2r, nullptr, p2, hz);
    agg16_kernel<false><<<NBUK, 256, 0, stream>>>(bcnt, tmp, p2, hz, b2, z);

    // decode
    decode_kernel<<<(NL * 16 + 255) / 256, 256, 0, stream>>>(eli, eli + NL, z, out);
}